// Round 15
// baseline (199.938 us; speedup 1.0000x reference)
//
#include <hip/hip_runtime.h>
#include <hip/hip_fp16.h>

#define NN 50000
#define NE 800000
#define NEG 0.2f

typedef unsigned short ushort_t;

// unpack 8 halfs (uint4) and accumulate into va[0..7]
__device__ __forceinline__ void acc8(float* va, uint4 v) {
    const __half2* h = (const __half2*)&v;
#pragma unroll
    for (int j = 0; j < 4; ++j) {
        float2 f = __half22float2(h[j]);
        va[2 * j]     += f.x;
        va[2 * j + 1] += f.y;
    }
}
// dot of 8 halfs (uint4) with t[0..7]
__device__ __forceinline__ float dot8(uint4 v, const float* t, float acc) {
    const __half2* h = (const __half2*)&v;
#pragma unroll
    for (int j = 0; j < 4; ++j) {
        float2 f = __half22float2(h[j]);
        acc = fmaf(f.x, t[2 * j], acc);
        acc = fmaf(f.y, t[2 * j + 1], acc);
    }
    return acc;
}

// 1. feat -> fp16 mirror (gather payload), zero count
__global__ __launch_bounds__(256) void k_prep(const float* __restrict__ feat,
                                              __half* __restrict__ feat16,
                                              int* __restrict__ count) {
    int i = blockIdx.x * 256 + threadIdx.x;
    const float4 v = ((const float4*)feat)[i];
    __half2 a = __floats2half2_rn(v.x, v.y);
    __half2 b = __floats2half2_rn(v.z, v.w);
    ((uint2*)feat16)[i] = make_uint2(*(unsigned*)&a, *(unsigned*)&b);
    if (i < NN) count[i] = 0;
}

// 2. degree histogram + per-edge rank
__global__ __launch_bounds__(256) void k_count(const int* __restrict__ dst,
                                               int* __restrict__ count,
                                               int* __restrict__ rank) {
    int e = blockIdx.x * 256 + threadIdx.x;
    rank[e] = atomicAdd(&count[dst[e]], 1);
}

// 3. exclusive prefix scan of count -> rowptr
__global__ __launch_bounds__(256) void k_scan(const int* __restrict__ count,
                                              int* __restrict__ rowptr) {
    __shared__ int sdata[256];
    const int tid = threadIdx.x, b = blockIdx.x;
    int pre = 0;
    for (int i = tid; i < b * 256; i += 256) pre += count[i];
    sdata[tid] = pre;
    __syncthreads();
    for (int off = 128; off; off >>= 1) {
        if (tid < off) sdata[tid] += sdata[tid + off];
        __syncthreads();
    }
    const int P = sdata[0];
    __syncthreads();
    const int idx = b * 256 + tid;
    const int c = (idx < NN) ? count[idx] : 0;
    sdata[tid] = c;
    __syncthreads();
    for (int off = 1; off < 256; off <<= 1) {
        int v = (tid >= off) ? sdata[tid - off] : 0;
        __syncthreads();
        sdata[tid] += v;
        __syncthreads();
    }
    if (idx < NN) rowptr[idx] = P + sdata[tid] - c;   // exclusive
}

// 4. fill CSR src list only (pos eliminated; remap recomputes it from rank)
__global__ __launch_bounds__(256) void k_fill(const int* __restrict__ src,
                                              const int* __restrict__ dst,
                                              const int* __restrict__ rowptr,
                                              const int* __restrict__ rank,
                                              ushort_t* __restrict__ esrc) {
    int e = blockIdx.x * 256 + threadIdx.x;
    esrc[rowptr[dst[e]] + rank[e]] = (ushort_t)src[e];
}

// 5. fused gather-aggregate(feat16) + GEMM, SAFE epilogue (r14-proven
//    pattern): float4 LDS stores -> __syncthreads() -> float4 broadcast
//    reads -> FMA with W held in 16 float4 VGPRs. Types consistent and a
//    real barrier on both sides of the LDS reuse -> no TBAA/ordering
//    hazard (the r9-r11 bug). LDS = 1 KB (vs 17.9 KB in r12).
__global__ __launch_bounds__(256) void k_aggemm2(const __half* __restrict__ feat16,
                                                 const float* __restrict__ W,
                                                 const int* __restrict__ rowptr,
                                                 const int* __restrict__ count,
                                                 const ushort_t* __restrict__ esrc,
                                                 float* __restrict__ hagg,
                                                 __half* __restrict__ hagg16) {
    __shared__ float4 sF4[4][16];               // per-wave aggregated row
    const int lane = threadIdx.x, w = threadIdx.y;
    const int g = lane >> 3, il = lane & 7;     // 8 subgroups of 8 lanes
    const float4* W4 = (const float4*)W;
    float4 wr[16];                              // W[lane][0..63]
#pragma unroll
    for (int k = 0; k < 16; ++k) wr[k] = W4[lane * 16 + k];

    const uint4* F16 = (const uint4*)feat16;    // row = 8 uint4
    for (int dd = 0; dd < 8; dd += 4) {         // uniform: all waves iterate
        const int d = blockIdx.x * 8 + dd + w;  // NN % 8 == 0
        const int start = rowptr[d], len = count[d];
        float va[8];
#pragma unroll
        for (int j = 0; j < 8; ++j) va[j] = 0.f;
        for (int base = 0; base < len; base += 64) {
            const int nb = min(64, len - base);
            int sid = (lane < nb) ? (int)esrc[start + base + lane] : 0;
            for (int sub = 0; sub < nb; sub += 16) {
                const int slot0 = sub + g;
                const int slot1 = sub + 8 + g;
                int s0 = __shfl(sid, slot0 & 63, 64);   // unconditional
                int s1 = __shfl(sid, slot1 & 63, 64);
                if (slot0 < nb) acc8(va, F16[(size_t)s0 * 8 + il]);
                if (slot1 < nb) acc8(va, F16[(size_t)s1 * 8 + il]);
            }
        }
#pragma unroll
        for (int off = 8; off < 64; off <<= 1)
#pragma unroll
            for (int j = 0; j < 8; ++j) va[j] += __shfl_xor(va[j], off, 64);
        if (g == 0) {                           // lane il holds dims 8il..8il+7
            sF4[w][il * 2]     = make_float4(va[0], va[1], va[2], va[3]);
            sF4[w][il * 2 + 1] = make_float4(va[4], va[5], va[6], va[7]);
        }
        __syncthreads();                        // fence: stores visible+ordered
        float o = 0.f;
#pragma unroll
        for (int k = 0; k < 16; ++k) {
            float4 f = sF4[w][k];               // broadcast ds_read_b128
            o = fmaf(wr[k].x, f.x, o);
            o = fmaf(wr[k].y, f.y, o);
            o = fmaf(wr[k].z, f.z, o);
            o = fmaf(wr[k].w, f.w, o);
        }
        hagg[(size_t)d * 64 + lane] = o;
        hagg16[(size_t)d * 64 + lane] = __float2half(o);
        __syncthreads();                        // protect sF4 before next dd
    }
}

// 6. fused edge-dot + leaky-relu + softmax — BYTE-EXACT r8 version (proven).
__global__ __launch_bounds__(256) void k_soft(const float* __restrict__ hagg,
                                              const __half* __restrict__ hagg16,
                                              const int* __restrict__ rowptr,
                                              const int* __restrict__ count,
                                              const ushort_t* __restrict__ esrc,
                                              float* __restrict__ ebuf) {
    __shared__ float sT[4][64];
    const int lane = threadIdx.x, w = threadIdx.y;
    const int q = lane & 3, slot = lane >> 2;
    const int d = blockIdx.x * 4 + w;           // NN % 4 == 0
    const int start = rowptr[d], len = count[d];
    sT[w][lane] = tanhf(hagg[(size_t)d * 64 + lane]);
    __syncthreads();
    float tq[16];                               // dims 16q .. 16q+15
#pragma unroll
    for (int j = 0; j < 16; ++j) tq[j] = sT[w][16 * q + j];

    const uint4* H16 = (const uint4*)hagg16;    // row = 8 uint4
    if (len == 0) return;

    if (len <= 128) {                            // fast path (~always)
        float rev[8];
        float m = -3.0e38f;
#pragma unroll
        for (int it = 0; it < 8; ++it) {
            rev[it] = -3.0e38f;
            const int base = it * 16;
            if (base + slot < len) {             // quad-uniform predicate
                const int p = start + base + slot;
                const int s = (int)esrc[p];
                uint4 v0 = H16[(size_t)s * 8 + 2 * q];
                uint4 v1 = H16[(size_t)s * 8 + 2 * q + 1];
                float acc = dot8(v0, tq, 0.f);
                acc = dot8(v1, tq + 8, acc);
                acc += __shfl_xor(acc, 1, 64);   // quad-internal
                acc += __shfl_xor(acc, 2, 64);
                rev[it] = acc >= 0.f ? acc : NEG * acc;
                m = fmaxf(m, rev[it]);
            }
        }
#pragma unroll
        for (int off = 4; off < 64; off <<= 1) m = fmaxf(m, __shfl_xor(m, off, 64));
        float ss = 0.f;
#pragma unroll
        for (int it = 0; it < 8; ++it) {
            float x = expf(rev[it] - m);         // invalid slots underflow to 0
            ss += x;
            rev[it] = x;
        }
#pragma unroll
        for (int off = 1; off < 64; off <<= 1) ss += __shfl_xor(ss, off, 64);
        const float inv = 4.f / ss;              // each edge counted by 4 lanes
#pragma unroll
        for (int it = 0; it < 8; ++it) {
            const int base = it * 16;
            if (base + slot < len && q == 0)
                ebuf[start + base + slot] = rev[it] * inv;
        }
    } else {                                     // slow path (rare long rows)
        float m = -3.0e38f;
        for (int base = 0; base < len; base += 16) {
            if (base + slot < len) {
                const int p = start + base + slot;
                const int s = (int)esrc[p];
                uint4 v0 = H16[(size_t)s * 8 + 2 * q];
                uint4 v1 = H16[(size_t)s * 8 + 2 * q + 1];
                float acc = dot8(v0, tq, 0.f);
                acc = dot8(v1, tq + 8, acc);
                acc += __shfl_xor(acc, 1, 64);
                acc += __shfl_xor(acc, 2, 64);
                float ev = acc >= 0.f ? acc : NEG * acc;
                m = fmaxf(m, ev);
                if (q == 0) ebuf[p] = ev;
            }
        }
#pragma unroll
        for (int off = 4; off < 64; off <<= 1) m = fmaxf(m, __shfl_xor(m, off, 64));
        float ss = 0.f;
        for (int base = 0; base < len; base += 64) {
            int idx = base + lane;
            float x = (idx < len) ? expf(ebuf[start + idx] - m) : 0.f;
#pragma unroll
            for (int off = 1; off < 64; off <<= 1) x += __shfl_xor(x, off, 64);
            ss += x;
        }
        const float inv = 1.f / ss;
        for (int base = 0; base < len; base += 64) {
            int idx = base + lane;
            if (idx < len)
                ebuf[start + idx] = expf(ebuf[start + idx] - m) * inv;
        }
    }
}

// 7. permutation gather, 4 edges/thread: e_soft[e] = ebuf[rowptr[dst]+rank]
__global__ __launch_bounds__(256) void k_remap(const int* __restrict__ dst,
                                               const int* __restrict__ rank,
                                               const int* __restrict__ rowptr,
                                               const float* __restrict__ ebuf,
                                               float* __restrict__ out_e) {
    int i = blockIdx.x * 256 + threadIdx.x;     // i indexes groups of 4
    if (i >= NE / 4) return;
    int4 d4 = ((const int4*)dst)[i];
    int4 r4 = ((const int4*)rank)[i];
    float4 r;
    r.x = ebuf[rowptr[d4.x] + r4.x];
    r.y = ebuf[rowptr[d4.y] + r4.y];
    r.z = ebuf[rowptr[d4.z] + r4.z];
    r.w = ebuf[rowptr[d4.w] + r4.w];
    ((float4*)out_e)[i] = r;
}

extern "C" void kernel_launch(void* const* d_in, const int* in_sizes, int n_in,
                              void* d_out, int out_size, void* d_ws, size_t ws_size,
                              hipStream_t stream) {
    const float* feat = (const float*)d_in[0];
    const float* W    = (const float*)d_in[1];
    const int*   src  = (const int*)d_in[2];
    const int*   dst  = (const int*)d_in[3];

    float* out    = (float*)d_out;
    float* hagg   = out;               // NN*64
    float* e_soft = out + NN * 64;     // NE

    float*    ebuf   = (float*)d_ws;              // NE f32
    int*      rank   = (int*)(ebuf + NE);         // NE
    int*      count  = rank + NE;                 // NN
    int*      rowptr = count + NN;                // NN
    ushort_t* esrc   = (ushort_t*)(rowptr + NN);  // NE ushort
    __half*   feat16 = (__half*)(esrc + NE);      // NN*64 fp16
    __half*   hagg16 = feat16 + NN * 64;          // NN*64 fp16

    dim3 b64x4(64, 4);
    k_prep   <<<NN * 64 / 1024, 256, 0, stream>>>(feat, feat16, count);
    k_count  <<<NE / 256, 256, 0, stream>>>(dst, count, rank);
    k_scan   <<<(NN + 255) / 256, 256, 0, stream>>>(count, rowptr);
    k_fill   <<<NE / 256, 256, 0, stream>>>(src, dst, rowptr, rank, esrc);
    k_aggemm2<<<NN / 8, b64x4, 0, stream>>>(feat16, W, rowptr, count, esrc,
                                            hagg, hagg16);
    k_soft   <<<NN / 4, b64x4, 0, stream>>>(hagg, hagg16, rowptr, count, esrc, ebuf);
    k_remap  <<<(NE / 4 + 255) / 256, 256, 0, stream>>>(dst, rank, rowptr,
                                                        ebuf, e_soft);
}

// Round 16
// 197.869 us; speedup vs baseline: 1.0105x; 1.0105x over previous
//
#include <hip/hip_runtime.h>
#include <hip/hip_fp16.h>

#define NN 50000
#define NE 800000
#define NEG 0.2f

typedef unsigned short ushort_t;

// unpack 8 halfs (uint4) and accumulate into va[0..7]
__device__ __forceinline__ void acc8(float* va, uint4 v) {
    const __half2* h = (const __half2*)&v;
#pragma unroll
    for (int j = 0; j < 4; ++j) {
        float2 f = __half22float2(h[j]);
        va[2 * j]     += f.x;
        va[2 * j + 1] += f.y;
    }
}
// dot of 8 halfs (uint4) with t[0..7]
__device__ __forceinline__ float dot8(uint4 v, const float* t, float acc) {
    const __half2* h = (const __half2*)&v;
#pragma unroll
    for (int j = 0; j < 4; ++j) {
        float2 f = __half22float2(h[j]);
        acc = fmaf(f.x, t[2 * j], acc);
        acc = fmaf(f.y, t[2 * j + 1], acc);
    }
    return acc;
}

// 1. feat -> fp16 mirror (gather payload), zero count
__global__ __launch_bounds__(256) void k_prep(const float* __restrict__ feat,
                                              __half* __restrict__ feat16,
                                              int* __restrict__ count) {
    int i = blockIdx.x * 256 + threadIdx.x;
    const float4 v = ((const float4*)feat)[i];
    __half2 a = __floats2half2_rn(v.x, v.y);
    __half2 b = __floats2half2_rn(v.z, v.w);
    ((uint2*)feat16)[i] = make_uint2(*(unsigned*)&a, *(unsigned*)&b);
    if (i < NN) count[i] = 0;
}

// 2. degree histogram + per-edge rank
__global__ __launch_bounds__(256) void k_count(const int* __restrict__ dst,
                                               int* __restrict__ count,
                                               int* __restrict__ rank) {
    int e = blockIdx.x * 256 + threadIdx.x;
    rank[e] = atomicAdd(&count[dst[e]], 1);
}

// 3. exclusive prefix scan of count -> rowptr
__global__ __launch_bounds__(256) void k_scan(const int* __restrict__ count,
                                              int* __restrict__ rowptr) {
    __shared__ int sdata[256];
    const int tid = threadIdx.x, b = blockIdx.x;
    int pre = 0;
    for (int i = tid; i < b * 256; i += 256) pre += count[i];
    sdata[tid] = pre;
    __syncthreads();
    for (int off = 128; off; off >>= 1) {
        if (tid < off) sdata[tid] += sdata[tid + off];
        __syncthreads();
    }
    const int P = sdata[0];
    __syncthreads();
    const int idx = b * 256 + tid;
    const int c = (idx < NN) ? count[idx] : 0;
    sdata[tid] = c;
    __syncthreads();
    for (int off = 1; off < 256; off <<= 1) {
        int v = (tid >= off) ? sdata[tid - off] : 0;
        __syncthreads();
        sdata[tid] += v;
        __syncthreads();
    }
    if (idx < NN) rowptr[idx] = P + sdata[tid] - c;   // exclusive
}

// 4. fill CSR src list only (pos eliminated; remap recomputes from rank)
__global__ __launch_bounds__(256) void k_fill(const int* __restrict__ src,
                                              const int* __restrict__ dst,
                                              const int* __restrict__ rowptr,
                                              const int* __restrict__ rank,
                                              ushort_t* __restrict__ esrc) {
    int e = blockIdx.x * 256 + threadIdx.x;
    esrc[rowptr[dst[e]] + rank[e]] = (ushort_t)src[e];
}

// 5. fused gather-aggregate(feat16) + GEMM, r12 structure (wave-independent,
//    NO in-loop barrier) with the SAFE epilogue:
//    - sF4 written AND read as native float4 on the same array (may-alias ->
//      compiler preserves order; same-wave DS ops are in-order in HW).
//      [r9-r11 bug was a float<->float4 cast mismatch hiding the dep: NEVER
//      read LDS through a differently-typed cast than it was written.]
//    - asm memory fence between store and load as belt-and-braces.
//    - W direct global->16 float4 VGPRs (r10/r11 A/B proved this path fine).
//    DS-ops/dst: 2x b128 write + 16x b128 broadcast read (vs 128 scalar).
__global__ __launch_bounds__(256) void k_aggemm(const __half* __restrict__ feat16,
                                                const float* __restrict__ W,
                                                const int* __restrict__ rowptr,
                                                const int* __restrict__ count,
                                                const ushort_t* __restrict__ esrc,
                                                float* __restrict__ hagg,
                                                __half* __restrict__ hagg16) {
    __shared__ float4 sF4[4][16];               // per-wave aggregated row
    const int lane = threadIdx.x, w = threadIdx.y;
    const int g = lane >> 3, il = lane & 7;     // 8 subgroups of 8 lanes
    const float4* W4 = (const float4*)W;
    float4 wr[16];                              // W[lane][0..63]
#pragma unroll
    for (int k = 0; k < 16; ++k) wr[k] = W4[lane * 16 + k];

    const uint4* F16 = (const uint4*)feat16;    // row = 8 uint4
    for (int dd = 0; dd < 8; dd += 4) {
        const int d = blockIdx.x * 8 + dd + w;  // NN % 8 == 0
        const int start = rowptr[d], len = count[d];
        float va[8];
#pragma unroll
        for (int j = 0; j < 8; ++j) va[j] = 0.f;
        for (int base = 0; base < len; base += 64) {
            const int nb = min(64, len - base);
            int sid = (lane < nb) ? (int)esrc[start + base + lane] : 0;
            for (int sub = 0; sub < nb; sub += 16) {
                const int slot0 = sub + g;
                const int slot1 = sub + 8 + g;
                int s0 = __shfl(sid, slot0 & 63, 64);   // unconditional
                int s1 = __shfl(sid, slot1 & 63, 64);
                if (slot0 < nb) acc8(va, F16[(size_t)s0 * 8 + il]);
                if (slot1 < nb) acc8(va, F16[(size_t)s1 * 8 + il]);
            }
        }
#pragma unroll
        for (int off = 8; off < 64; off <<= 1)
#pragma unroll
            for (int j = 0; j < 8; ++j) va[j] += __shfl_xor(va[j], off, 64);
        if (g == 0) {                           // lane il holds dims 8il..8il+7
            sF4[w][il * 2]     = make_float4(va[0], va[1], va[2], va[3]);
            sF4[w][il * 2 + 1] = make_float4(va[4], va[5], va[6], va[7]);
        }
        asm volatile("" ::: "memory");          // compiler fence: no hoisting
        float o = 0.f;
#pragma unroll
        for (int k = 0; k < 16; ++k) {
            float4 f = sF4[w][k];               // broadcast ds_read_b128
            o = fmaf(wr[k].x, f.x, o);
            o = fmaf(wr[k].y, f.y, o);
            o = fmaf(wr[k].z, f.z, o);
            o = fmaf(wr[k].w, f.w, o);
        }
        hagg[(size_t)d * 64 + lane] = o;
        hagg16[(size_t)d * 64 + lane] = __float2half(o);
        asm volatile("" ::: "memory");          // keep sF4 stores of next dd below
    }
}

// 6. fused edge-dot + leaky-relu + softmax — BYTE-EXACT r8 version (proven).
__global__ __launch_bounds__(256) void k_soft(const float* __restrict__ hagg,
                                              const __half* __restrict__ hagg16,
                                              const int* __restrict__ rowptr,
                                              const int* __restrict__ count,
                                              const ushort_t* __restrict__ esrc,
                                              float* __restrict__ ebuf) {
    __shared__ float sT[4][64];
    const int lane = threadIdx.x, w = threadIdx.y;
    const int q = lane & 3, slot = lane >> 2;
    const int d = blockIdx.x * 4 + w;           // NN % 4 == 0
    const int start = rowptr[d], len = count[d];
    sT[w][lane] = tanhf(hagg[(size_t)d * 64 + lane]);
    __syncthreads();
    float tq[16];                               // dims 16q .. 16q+15
#pragma unroll
    for (int j = 0; j < 16; ++j) tq[j] = sT[w][16 * q + j];

    const uint4* H16 = (const uint4*)hagg16;    // row = 8 uint4
    if (len == 0) return;

    if (len <= 128) {                            // fast path (~always)
        float rev[8];
        float m = -3.0e38f;
#pragma unroll
        for (int it = 0; it < 8; ++it) {
            rev[it] = -3.0e38f;
            const int base = it * 16;
            if (base + slot < len) {             // quad-uniform predicate
                const int p = start + base + slot;
                const int s = (int)esrc[p];
                uint4 v0 = H16[(size_t)s * 8 + 2 * q];
                uint4 v1 = H16[(size_t)s * 8 + 2 * q + 1];
                float acc = dot8(v0, tq, 0.f);
                acc = dot8(v1, tq + 8, acc);
                acc += __shfl_xor(acc, 1, 64);   // quad-internal
                acc += __shfl_xor(acc, 2, 64);
                rev[it] = acc >= 0.f ? acc : NEG * acc;
                m = fmaxf(m, rev[it]);
            }
        }
#pragma unroll
        for (int off = 4; off < 64; off <<= 1) m = fmaxf(m, __shfl_xor(m, off, 64));
        float ss = 0.f;
#pragma unroll
        for (int it = 0; it < 8; ++it) {
            float x = expf(rev[it] - m);         // invalid slots underflow to 0
            ss += x;
            rev[it] = x;
        }
#pragma unroll
        for (int off = 1; off < 64; off <<= 1) ss += __shfl_xor(ss, off, 64);
        const float inv = 4.f / ss;              // each edge counted by 4 lanes
#pragma unroll
        for (int it = 0; it < 8; ++it) {
            const int base = it * 16;
            if (base + slot < len && q == 0)
                ebuf[start + base + slot] = rev[it] * inv;
        }
    } else {                                     // slow path (rare long rows)
        float m = -3.0e38f;
        for (int base = 0; base < len; base += 16) {
            if (base + slot < len) {
                const int p = start + base + slot;
                const int s = (int)esrc[p];
                uint4 v0 = H16[(size_t)s * 8 + 2 * q];
                uint4 v1 = H16[(size_t)s * 8 + 2 * q + 1];
                float acc = dot8(v0, tq, 0.f);
                acc = dot8(v1, tq + 8, acc);
                acc += __shfl_xor(acc, 1, 64);
                acc += __shfl_xor(acc, 2, 64);
                float ev = acc >= 0.f ? acc : NEG * acc;
                m = fmaxf(m, ev);
                if (q == 0) ebuf[p] = ev;
            }
        }
#pragma unroll
        for (int off = 4; off < 64; off <<= 1) m = fmaxf(m, __shfl_xor(m, off, 64));
        float ss = 0.f;
        for (int base = 0; base < len; base += 64) {
            int idx = base + lane;
            float x = (idx < len) ? expf(ebuf[start + idx] - m) : 0.f;
#pragma unroll
            for (int off = 1; off < 64; off <<= 1) x += __shfl_xor(x, off, 64);
            ss += x;
        }
        const float inv = 1.f / ss;
        for (int base = 0; base < len; base += 64) {
            int idx = base + lane;
            if (idx < len)
                ebuf[start + idx] = expf(ebuf[start + idx] - m) * inv;
        }
    }
}

// 7. permutation gather, 4 edges/thread: e_soft[e] = ebuf[rowptr[dst]+rank]
__global__ __launch_bounds__(256) void k_remap(const int* __restrict__ dst,
                                               const int* __restrict__ rank,
                                               const int* __restrict__ rowptr,
                                               const float* __restrict__ ebuf,
                                               float* __restrict__ out_e) {
    int i = blockIdx.x * 256 + threadIdx.x;     // i indexes groups of 4
    if (i >= NE / 4) return;
    int4 d4 = ((const int4*)dst)[i];
    int4 r4 = ((const int4*)rank)[i];
    float4 r;
    r.x = ebuf[rowptr[d4.x] + r4.x];
    r.y = ebuf[rowptr[d4.y] + r4.y];
    r.z = ebuf[rowptr[d4.z] + r4.z];
    r.w = ebuf[rowptr[d4.w] + r4.w];
    ((float4*)out_e)[i] = r;
}

extern "C" void kernel_launch(void* const* d_in, const int* in_sizes, int n_in,
                              void* d_out, int out_size, void* d_ws, size_t ws_size,
                              hipStream_t stream) {
    const float* feat = (const float*)d_in[0];
    const float* W    = (const float*)d_in[1];
    const int*   src  = (const int*)d_in[2];
    const int*   dst  = (const int*)d_in[3];

    float* out    = (float*)d_out;
    float* hagg   = out;               // NN*64
    float* e_soft = out + NN * 64;     // NE

    float*    ebuf   = (float*)d_ws;              // NE f32
    int*      rank   = (int*)(ebuf + NE);         // NE
    int*      count  = rank + NE;                 // NN
    int*      rowptr = count + NN;                // NN
    ushort_t* esrc   = (ushort_t*)(rowptr + NN);  // NE ushort
    __half*   feat16 = (__half*)(esrc + NE);      // NN*64 fp16
    __half*   hagg16 = feat16 + NN * 64;          // NN*64 fp16

    dim3 b64x4(64, 4);
    k_prep  <<<NN * 64 / 1024, 256, 0, stream>>>(feat, feat16, count);
    k_count <<<NE / 256, 256, 0, stream>>>(dst, count, rank);
    k_scan  <<<(NN + 255) / 256, 256, 0, stream>>>(count, rowptr);
    k_fill  <<<NE / 256, 256, 0, stream>>>(src, dst, rowptr, rank, esrc);
    k_aggemm<<<NN / 8, b64x4, 0, stream>>>(feat16, W, rowptr, count, esrc,
                                           hagg, hagg16);
    k_soft  <<<NN / 4, b64x4, 0, stream>>>(hagg, hagg16, rowptr, count, esrc, ebuf);
    k_remap <<<(NE / 4 + 255) / 256, 256, 0, stream>>>(dst, rank, rowptr,
                                                       ebuf, e_soft);
}

// Round 17
// 169.752 us; speedup vs baseline: 1.1778x; 1.1656x over previous
//
#include <hip/hip_runtime.h>
#include <hip/hip_fp16.h>

#define NN 50000
#define NE 800000
#define NEG 0.2f

typedef unsigned short ushort_t;

// unpack 8 halfs (uint4) and accumulate into va[0..7]
__device__ __forceinline__ void acc8(float* va, uint4 v) {
    const __half2* h = (const __half2*)&v;
#pragma unroll
    for (int j = 0; j < 4; ++j) {
        float2 f = __half22float2(h[j]);
        va[2 * j]     += f.x;
        va[2 * j + 1] += f.y;
    }
}
// dot of 8 halfs (uint4) with t[0..7]
__device__ __forceinline__ float dot8(uint4 v, const float* t, float acc) {
    const __half2* h = (const __half2*)&v;
#pragma unroll
    for (int j = 0; j < 4; ++j) {
        float2 f = __half22float2(h[j]);
        acc = fmaf(f.x, t[2 * j], acc);
        acc = fmaf(f.y, t[2 * j + 1], acc);
    }
    return acc;
}

// 1. feat -> fp16 mirror (gather payload), zero count
__global__ __launch_bounds__(256) void k_prep(const float* __restrict__ feat,
                                              __half* __restrict__ feat16,
                                              int* __restrict__ count) {
    int i = blockIdx.x * 256 + threadIdx.x;
    const float4 v = ((const float4*)feat)[i];
    __half2 a = __floats2half2_rn(v.x, v.y);
    __half2 b = __floats2half2_rn(v.z, v.w);
    ((uint2*)feat16)[i] = make_uint2(*(unsigned*)&a, *(unsigned*)&b);
    if (i < NN) count[i] = 0;
}

// 2. degree histogram + per-edge rank
__global__ __launch_bounds__(256) void k_count(const int* __restrict__ dst,
                                               int* __restrict__ count,
                                               int* __restrict__ rank) {
    int e = blockIdx.x * 256 + threadIdx.x;
    rank[e] = atomicAdd(&count[dst[e]], 1);
}

// 3. exclusive prefix scan of count -> rowptr
__global__ __launch_bounds__(256) void k_scan(const int* __restrict__ count,
                                              int* __restrict__ rowptr) {
    __shared__ int sdata[256];
    const int tid = threadIdx.x, b = blockIdx.x;
    int pre = 0;
    for (int i = tid; i < b * 256; i += 256) pre += count[i];
    sdata[tid] = pre;
    __syncthreads();
    for (int off = 128; off; off >>= 1) {
        if (tid < off) sdata[tid] += sdata[tid + off];
        __syncthreads();
    }
    const int P = sdata[0];
    __syncthreads();
    const int idx = b * 256 + tid;
    const int c = (idx < NN) ? count[idx] : 0;
    sdata[tid] = c;
    __syncthreads();
    for (int off = 1; off < 256; off <<= 1) {
        int v = (tid >= off) ? sdata[tid - off] : 0;
        __syncthreads();
        sdata[tid] += v;
        __syncthreads();
    }
    if (idx < NN) rowptr[idx] = P + sdata[tid] - c;   // exclusive
}

// 4. fill CSR src list only (pos eliminated; remap recomputes from rank)
__global__ __launch_bounds__(256) void k_fill(const int* __restrict__ src,
                                              const int* __restrict__ dst,
                                              const int* __restrict__ rowptr,
                                              const int* __restrict__ rank,
                                              ushort_t* __restrict__ esrc) {
    int e = blockIdx.x * 256 + threadIdx.x;
    esrc[rowptr[dst[e]] + rank[e]] = (ushort_t)src[e];
}

// 5. fused gather-aggregate(feat16) + GEMM — BYTE-EXACT r12 version (the
//    empirical optimum: 50 µs). Ledger of failed alternatives: split-GEMM
//    (latency-bound, 50 µs alone), barrier epilogue (+30), asm-fence
//    epilogue (compiler drops W from regs, +29), typed-cast epilogues
//    (wrong answers). Scalar LDS W-stage + scalar sFw stores/reads stays.
__global__ __launch_bounds__(256) void k_aggemm(const __half* __restrict__ feat16,
                                                const float* __restrict__ W,
                                                const int* __restrict__ rowptr,
                                                const int* __restrict__ count,
                                                const ushort_t* __restrict__ esrc,
                                                float* __restrict__ hagg,
                                                __half* __restrict__ hagg16) {
    __shared__ float sWt[64][65];   // sWt[i][o] = W[o][i]
    __shared__ float sFw[4][64];    // per-wave slice (no cross-wave barrier)
    const int lane = threadIdx.x, w = threadIdx.y;
    const int g = lane >> 3, il = lane & 7;     // 8 subgroups of 8 lanes
    const int t = w * 64 + lane;
    for (int k = t; k < 4096; k += 256) sWt[k & 63][k >> 6] = W[k];
    __syncthreads();

    const uint4* F16 = (const uint4*)feat16;    // row = 8 uint4
    for (int dd = 0; dd < 8; dd += 4) {
        const int d = blockIdx.x * 8 + dd + w;  // NN % 8 == 0 -> always valid
        const int start = rowptr[d], len = count[d];
        float va[8];
#pragma unroll
        for (int j = 0; j < 8; ++j) va[j] = 0.f;
        for (int base = 0; base < len; base += 64) {
            const int nb = min(64, len - base);
            int sid = (lane < nb) ? (int)esrc[start + base + lane] : 0;
            for (int sub = 0; sub < nb; sub += 16) {
                const int slot0 = sub + g;
                const int slot1 = sub + 8 + g;
                int s0 = __shfl(sid, slot0 & 63, 64);   // unconditional
                int s1 = __shfl(sid, slot1 & 63, 64);
                if (slot0 < nb) acc8(va, F16[(size_t)s0 * 8 + il]);
                if (slot1 < nb) acc8(va, F16[(size_t)s1 * 8 + il]);
            }
        }
#pragma unroll
        for (int off = 8; off < 64; off <<= 1)
#pragma unroll
            for (int j = 0; j < 8; ++j) va[j] += __shfl_xor(va[j], off, 64);
        if (g == 0) {
#pragma unroll
            for (int j = 0; j < 8; ++j) sFw[w][il * 8 + j] = va[j];
        }
        // wave-internal LDS RAW, same-typed accesses (compiler-visible dep)
        float o = 0.f;
#pragma unroll
        for (int i = 0; i < 64; ++i) o = fmaf(sFw[w][i], sWt[i][lane], o);
        hagg[(size_t)d * 64 + lane] = o;
        hagg16[(size_t)d * 64 + lane] = __float2half(o);
    }
}

// 6. fused edge-dot + leaky-relu + softmax — BYTE-EXACT r8 version (proven).
__global__ __launch_bounds__(256) void k_soft(const float* __restrict__ hagg,
                                              const __half* __restrict__ hagg16,
                                              const int* __restrict__ rowptr,
                                              const int* __restrict__ count,
                                              const ushort_t* __restrict__ esrc,
                                              float* __restrict__ ebuf) {
    __shared__ float sT[4][64];
    const int lane = threadIdx.x, w = threadIdx.y;
    const int q = lane & 3, slot = lane >> 2;
    const int d = blockIdx.x * 4 + w;           // NN % 4 == 0
    const int start = rowptr[d], len = count[d];
    sT[w][lane] = tanhf(hagg[(size_t)d * 64 + lane]);
    __syncthreads();
    float tq[16];                               // dims 16q .. 16q+15
#pragma unroll
    for (int j = 0; j < 16; ++j) tq[j] = sT[w][16 * q + j];

    const uint4* H16 = (const uint4*)hagg16;    // row = 8 uint4
    if (len == 0) return;

    if (len <= 128) {                            // fast path (~always)
        float rev[8];
        float m = -3.0e38f;
#pragma unroll
        for (int it = 0; it < 8; ++it) {
            rev[it] = -3.0e38f;
            const int base = it * 16;
            if (base + slot < len) {             // quad-uniform predicate
                const int p = start + base + slot;
                const int s = (int)esrc[p];
                uint4 v0 = H16[(size_t)s * 8 + 2 * q];
                uint4 v1 = H16[(size_t)s * 8 + 2 * q + 1];
                float acc = dot8(v0, tq, 0.f);
                acc = dot8(v1, tq + 8, acc);
                acc += __shfl_xor(acc, 1, 64);   // quad-internal
                acc += __shfl_xor(acc, 2, 64);
                rev[it] = acc >= 0.f ? acc : NEG * acc;
                m = fmaxf(m, rev[it]);
            }
        }
#pragma unroll
        for (int off = 4; off < 64; off <<= 1) m = fmaxf(m, __shfl_xor(m, off, 64));
        float ss = 0.f;
#pragma unroll
        for (int it = 0; it < 8; ++it) {
            float x = expf(rev[it] - m);         // invalid slots underflow to 0
            ss += x;
            rev[it] = x;
        }
#pragma unroll
        for (int off = 1; off < 64; off <<= 1) ss += __shfl_xor(ss, off, 64);
        const float inv = 4.f / ss;              // each edge counted by 4 lanes
#pragma unroll
        for (int it = 0; it < 8; ++it) {
            const int base = it * 16;
            if (base + slot < len && q == 0)
                ebuf[start + base + slot] = rev[it] * inv;
        }
    } else {                                     // slow path (rare long rows)
        float m = -3.0e38f;
        for (int base = 0; base < len; base += 16) {
            if (base + slot < len) {
                const int p = start + base + slot;
                const int s = (int)esrc[p];
                uint4 v0 = H16[(size_t)s * 8 + 2 * q];
                uint4 v1 = H16[(size_t)s * 8 + 2 * q + 1];
                float acc = dot8(v0, tq, 0.f);
                acc = dot8(v1, tq + 8, acc);
                acc += __shfl_xor(acc, 1, 64);
                acc += __shfl_xor(acc, 2, 64);
                float ev = acc >= 0.f ? acc : NEG * acc;
                m = fmaxf(m, ev);
                if (q == 0) ebuf[p] = ev;
            }
        }
#pragma unroll
        for (int off = 4; off < 64; off <<= 1) m = fmaxf(m, __shfl_xor(m, off, 64));
        float ss = 0.f;
        for (int base = 0; base < len; base += 64) {
            int idx = base + lane;
            float x = (idx < len) ? expf(ebuf[start + idx] - m) : 0.f;
#pragma unroll
            for (int off = 1; off < 64; off <<= 1) x += __shfl_xor(x, off, 64);
            ss += x;
        }
        const float inv = 1.f / ss;
        for (int base = 0; base < len; base += 64) {
            int idx = base + lane;
            if (idx < len)
                ebuf[start + idx] = expf(ebuf[start + idx] - m) * inv;
        }
    }
}

// 7. permutation gather, 4 edges/thread: e_soft[e] = ebuf[rowptr[dst]+rank]
__global__ __launch_bounds__(256) void k_remap(const int* __restrict__ dst,
                                               const int* __restrict__ rank,
                                               const int* __restrict__ rowptr,
                                               const float* __restrict__ ebuf,
                                               float* __restrict__ out_e) {
    int i = blockIdx.x * 256 + threadIdx.x;     // i indexes groups of 4
    if (i >= NE / 4) return;
    int4 d4 = ((const int4*)dst)[i];
    int4 r4 = ((const int4*)rank)[i];
    float4 r;
    r.x = ebuf[rowptr[d4.x] + r4.x];
    r.y = ebuf[rowptr[d4.y] + r4.y];
    r.z = ebuf[rowptr[d4.z] + r4.z];
    r.w = ebuf[rowptr[d4.w] + r4.w];
    ((float4*)out_e)[i] = r;
}

extern "C" void kernel_launch(void* const* d_in, const int* in_sizes, int n_in,
                              void* d_out, int out_size, void* d_ws, size_t ws_size,
                              hipStream_t stream) {
    const float* feat = (const float*)d_in[0];
    const float* W    = (const float*)d_in[1];
    const int*   src  = (const int*)d_in[2];
    const int*   dst  = (const int*)d_in[3];

    float* out    = (float*)d_out;
    float* hagg   = out;               // NN*64
    float* e_soft = out + NN * 64;     // NE

    float*    ebuf   = (float*)d_ws;              // NE f32
    int*      rank   = (int*)(ebuf + NE);         // NE
    int*      count  = rank + NE;                 // NN
    int*      rowptr = count + NN;                // NN
    ushort_t* esrc   = (ushort_t*)(rowptr + NN);  // NE ushort
    __half*   feat16 = (__half*)(esrc + NE);      // NN*64 fp16
    __half*   hagg16 = feat16 + NN * 64;          // NN*64 fp16

    dim3 b64x4(64, 4);
    k_prep  <<<NN * 64 / 1024, 256, 0, stream>>>(feat, feat16, count);
    k_count <<<NE / 256, 256, 0, stream>>>(dst, count, rank);
    k_scan  <<<(NN + 255) / 256, 256, 0, stream>>>(count, rowptr);
    k_fill  <<<NE / 256, 256, 0, stream>>>(src, dst, rowptr, rank, esrc);
    k_aggemm<<<NN / 8, b64x4, 0, stream>>>(feat16, W, rowptr, count, esrc,
                                           hagg, hagg16);
    k_soft  <<<NN / 4, b64x4, 0, stream>>>(hagg, hagg16, rowptr, count, esrc, ebuf);
    k_remap <<<(NE / 4 + 255) / 256, 256, 0, stream>>>(dst, rank, rowptr,
                                                       ebuf, e_soft);
}

// Round 18
// 166.091 us; speedup vs baseline: 1.2038x; 1.0220x over previous
//
#include <hip/hip_runtime.h>
#include <hip/hip_fp16.h>

#define NN 50000
#define NE 800000
#define NEG 0.2f

typedef unsigned short ushort_t;

// unpack 8 halfs (uint4) and accumulate into va[0..7]
__device__ __forceinline__ void acc8(float* va, uint4 v) {
    const __half2* h = (const __half2*)&v;
#pragma unroll
    for (int j = 0; j < 4; ++j) {
        float2 f = __half22float2(h[j]);
        va[2 * j]     += f.x;
        va[2 * j + 1] += f.y;
    }
}
// dot of 8 halfs (uint4) with t[0..7]
__device__ __forceinline__ float dot8(uint4 v, const float* t, float acc) {
    const __half2* h = (const __half2*)&v;
#pragma unroll
    for (int j = 0; j < 4; ++j) {
        float2 f = __half22float2(h[j]);
        acc = fmaf(f.x, t[2 * j], acc);
        acc = fmaf(f.y, t[2 * j + 1], acc);
    }
    return acc;
}

// 1. feat -> fp16 mirror (gather payload), zero count
__global__ __launch_bounds__(256) void k_prep(const float* __restrict__ feat,
                                              __half* __restrict__ feat16,
                                              int* __restrict__ count) {
    int i = blockIdx.x * 256 + threadIdx.x;
    const float4 v = ((const float4*)feat)[i];
    __half2 a = __floats2half2_rn(v.x, v.y);
    __half2 b = __floats2half2_rn(v.z, v.w);
    ((uint2*)feat16)[i] = make_uint2(*(unsigned*)&a, *(unsigned*)&b);
    if (i < NN) count[i] = 0;
}

// 2. degree histogram + per-edge rank
__global__ __launch_bounds__(256) void k_count(const int* __restrict__ dst,
                                               int* __restrict__ count,
                                               int* __restrict__ rank) {
    int e = blockIdx.x * 256 + threadIdx.x;
    rank[e] = atomicAdd(&count[dst[e]], 1);
}

// 3. exclusive prefix scan of count -> rowptr
__global__ __launch_bounds__(256) void k_scan(const int* __restrict__ count,
                                              int* __restrict__ rowptr) {
    __shared__ int sdata[256];
    const int tid = threadIdx.x, b = blockIdx.x;
    int pre = 0;
    for (int i = tid; i < b * 256; i += 256) pre += count[i];
    sdata[tid] = pre;
    __syncthreads();
    for (int off = 128; off; off >>= 1) {
        if (tid < off) sdata[tid] += sdata[tid + off];
        __syncthreads();
    }
    const int P = sdata[0];
    __syncthreads();
    const int idx = b * 256 + tid;
    const int c = (idx < NN) ? count[idx] : 0;
    sdata[tid] = c;
    __syncthreads();
    for (int off = 1; off < 256; off <<= 1) {
        int v = (tid >= off) ? sdata[tid - off] : 0;
        __syncthreads();
        sdata[tid] += v;
        __syncthreads();
    }
    if (idx < NN) rowptr[idx] = P + sdata[tid] - c;   // exclusive
}

// 4. fill CSR src list (no atomics) + pos[e]  (r12-exact; pos restored —
//    recomputing via rowptr gather in remap measured 2 µs slower)
__global__ __launch_bounds__(256) void k_fill(const int* __restrict__ src,
                                              const int* __restrict__ dst,
                                              const int* __restrict__ rowptr,
                                              const int* __restrict__ rank,
                                              ushort_t* __restrict__ esrc,
                                              int* __restrict__ pos) {
    int e = blockIdx.x * 256 + threadIdx.x;
    int p = rowptr[dst[e]] + rank[e];
    esrc[p] = (ushort_t)src[e];
    pos[e] = p;
}

// 5. fused gather-aggregate(feat16) + GEMM, DUAL-DST: each wave gathers its
//    TWO dsts concurrently (4 independent row-loads in flight vs 2) to
//    double memory-level parallelism in the latency-bound gather. Shuffles
//    unconditional; negative nb predicates are all-false (same semantics as
//    the proven single-dst loop). Epilogues: proven r12 scalar-LDS pattern,
//    back-to-back (same-typed same-array DS ops -> program-order dep).
__global__ __launch_bounds__(256) void k_aggemm(const __half* __restrict__ feat16,
                                                const float* __restrict__ W,
                                                const int* __restrict__ rowptr,
                                                const int* __restrict__ count,
                                                const ushort_t* __restrict__ esrc,
                                                float* __restrict__ hagg,
                                                __half* __restrict__ hagg16) {
    __shared__ float sWt[64][65];   // sWt[i][o] = W[o][i]
    __shared__ float sFw[4][64];    // per-wave slice
    const int lane = threadIdx.x, w = threadIdx.y;
    const int g = lane >> 3, il = lane & 7;     // 8 subgroups of 8 lanes
    const int t = w * 64 + lane;
    for (int k = t; k < 4096; k += 256) sWt[k & 63][k >> 6] = W[k];
    __syncthreads();

    const uint4* F16 = (const uint4*)feat16;    // row = 8 uint4
    const int d0 = blockIdx.x * 8 + w;          // NN % 8 == 0
    const int d1 = d0 + 4;
    const int s0r = rowptr[d0], l0 = count[d0];
    const int s1r = rowptr[d1], l1 = count[d1];
    float va0[8], va1[8];
#pragma unroll
    for (int j = 0; j < 8; ++j) { va0[j] = 0.f; va1[j] = 0.f; }

    const int lmax = max(l0, l1);
    for (int base = 0; base < lmax; base += 64) {
        const int nb0 = min(64, l0 - base);     // may be <= 0
        const int nb1 = min(64, l1 - base);
        int sid0 = (base + lane < l0) ? (int)esrc[s0r + base + lane] : 0;
        int sid1 = (base + lane < l1) ? (int)esrc[s1r + base + lane] : 0;
        const int nbm = max(nb0, nb1);
        for (int sub = 0; sub < nbm; sub += 16) {
            const int slot0 = sub + g;
            const int slot1 = sub + 8 + g;
            int a0 = __shfl(sid0, slot0 & 63, 64);   // all unconditional
            int a1 = __shfl(sid0, slot1 & 63, 64);
            int b0 = __shfl(sid1, slot0 & 63, 64);
            int b1 = __shfl(sid1, slot1 & 63, 64);
            if (slot0 < nb0) acc8(va0, F16[(size_t)a0 * 8 + il]);
            if (slot0 < nb1) acc8(va1, F16[(size_t)b0 * 8 + il]);
            if (slot1 < nb0) acc8(va0, F16[(size_t)a1 * 8 + il]);
            if (slot1 < nb1) acc8(va1, F16[(size_t)b1 * 8 + il]);
        }
    }
#pragma unroll
    for (int off = 8; off < 64; off <<= 1) {
#pragma unroll
        for (int j = 0; j < 8; ++j) {
            va0[j] += __shfl_xor(va0[j], off, 64);
            va1[j] += __shfl_xor(va1[j], off, 64);
        }
    }
    // epilogue dst0 (proven scalar-LDS pattern)
    if (g == 0) {
#pragma unroll
        for (int j = 0; j < 8; ++j) sFw[w][il * 8 + j] = va0[j];
    }
    float o0 = 0.f;
#pragma unroll
    for (int i = 0; i < 64; ++i) o0 = fmaf(sFw[w][i], sWt[i][lane], o0);
    hagg[(size_t)d0 * 64 + lane] = o0;
    hagg16[(size_t)d0 * 64 + lane] = __float2half(o0);
    // epilogue dst1 (stores after dst0's reads in program order, same type)
    if (g == 0) {
#pragma unroll
        for (int j = 0; j < 8; ++j) sFw[w][il * 8 + j] = va1[j];
    }
    float o1 = 0.f;
#pragma unroll
    for (int i = 0; i < 64; ++i) o1 = fmaf(sFw[w][i], sWt[i][lane], o1);
    hagg[(size_t)d1 * 64 + lane] = o1;
    hagg16[(size_t)d1 * 64 + lane] = __float2half(o1);
}

// 6. fused edge-dot + leaky-relu + softmax — BYTE-EXACT r8 version (proven).
__global__ __launch_bounds__(256) void k_soft(const float* __restrict__ hagg,
                                              const __half* __restrict__ hagg16,
                                              const int* __restrict__ rowptr,
                                              const int* __restrict__ count,
                                              const ushort_t* __restrict__ esrc,
                                              float* __restrict__ ebuf) {
    __shared__ float sT[4][64];
    const int lane = threadIdx.x, w = threadIdx.y;
    const int q = lane & 3, slot = lane >> 2;
    const int d = blockIdx.x * 4 + w;           // NN % 4 == 0
    const int start = rowptr[d], len = count[d];
    sT[w][lane] = tanhf(hagg[(size_t)d * 64 + lane]);
    __syncthreads();
    float tq[16];                               // dims 16q .. 16q+15
#pragma unroll
    for (int j = 0; j < 16; ++j) tq[j] = sT[w][16 * q + j];

    const uint4* H16 = (const uint4*)hagg16;    // row = 8 uint4
    if (len == 0) return;

    if (len <= 128) {                            // fast path (~always)
        float rev[8];
        float m = -3.0e38f;
#pragma unroll
        for (int it = 0; it < 8; ++it) {
            rev[it] = -3.0e38f;
            const int base = it * 16;
            if (base + slot < len) {             // quad-uniform predicate
                const int p = start + base + slot;
                const int s = (int)esrc[p];
                uint4 v0 = H16[(size_t)s * 8 + 2 * q];
                uint4 v1 = H16[(size_t)s * 8 + 2 * q + 1];
                float acc = dot8(v0, tq, 0.f);
                acc = dot8(v1, tq + 8, acc);
                acc += __shfl_xor(acc, 1, 64);   // quad-internal
                acc += __shfl_xor(acc, 2, 64);
                rev[it] = acc >= 0.f ? acc : NEG * acc;
                m = fmaxf(m, rev[it]);
            }
        }
#pragma unroll
        for (int off = 4; off < 64; off <<= 1) m = fmaxf(m, __shfl_xor(m, off, 64));
        float ss = 0.f;
#pragma unroll
        for (int it = 0; it < 8; ++it) {
            float x = expf(rev[it] - m);         // invalid slots underflow to 0
            ss += x;
            rev[it] = x;
        }
#pragma unroll
        for (int off = 1; off < 64; off <<= 1) ss += __shfl_xor(ss, off, 64);
        const float inv = 4.f / ss;              // each edge counted by 4 lanes
#pragma unroll
        for (int it = 0; it < 8; ++it) {
            const int base = it * 16;
            if (base + slot < len && q == 0)
                ebuf[start + base + slot] = rev[it] * inv;
        }
    } else {                                     // slow path (rare long rows)
        float m = -3.0e38f;
        for (int base = 0; base < len; base += 16) {
            if (base + slot < len) {
                const int p = start + base + slot;
                const int s = (int)esrc[p];
                uint4 v0 = H16[(size_t)s * 8 + 2 * q];
                uint4 v1 = H16[(size_t)s * 8 + 2 * q + 1];
                float acc = dot8(v0, tq, 0.f);
                acc = dot8(v1, tq + 8, acc);
                acc += __shfl_xor(acc, 1, 64);
                acc += __shfl_xor(acc, 2, 64);
                float ev = acc >= 0.f ? acc : NEG * acc;
                m = fmaxf(m, ev);
                if (q == 0) ebuf[p] = ev;
            }
        }
#pragma unroll
        for (int off = 4; off < 64; off <<= 1) m = fmaxf(m, __shfl_xor(m, off, 64));
        float ss = 0.f;
        for (int base = 0; base < len; base += 64) {
            int idx = base + lane;
            float x = (idx < len) ? expf(ebuf[start + idx] - m) : 0.f;
#pragma unroll
            for (int off = 1; off < 64; off <<= 1) x += __shfl_xor(x, off, 64);
            ss += x;
        }
        const float inv = 1.f / ss;
        for (int base = 0; base < len; base += 64) {
            int idx = base + lane;
            if (idx < len)
                ebuf[start + idx] = expf(ebuf[start + idx] - m) * inv;
        }
    }
}

// 7. permutation gather, 4 edges/thread: e_soft[e] = ebuf[pos[e]]
__global__ __launch_bounds__(256) void k_remap(const int* __restrict__ pos,
                                               const float* __restrict__ ebuf,
                                               float* __restrict__ out_e) {
    int i = blockIdx.x * 256 + threadIdx.x;     // i indexes groups of 4
    if (i >= NE / 4) return;
    int4 p4 = ((const int4*)pos)[i];
    float4 r;
    r.x = ebuf[p4.x];
    r.y = ebuf[p4.y];
    r.z = ebuf[p4.z];
    r.w = ebuf[p4.w];
    ((float4*)out_e)[i] = r;
}

extern "C" void kernel_launch(void* const* d_in, const int* in_sizes, int n_in,
                              void* d_out, int out_size, void* d_ws, size_t ws_size,
                              hipStream_t stream) {
    const float* feat = (const float*)d_in[0];
    const float* W    = (const float*)d_in[1];
    const int*   src  = (const int*)d_in[2];
    const int*   dst  = (const int*)d_in[3];

    float* out    = (float*)d_out;
    float* hagg   = out;               // NN*64
    float* e_soft = out + NN * 64;     // NE

    float*    ebuf   = (float*)d_ws;              // NE f32
    int*      pos    = (int*)(ebuf + NE);         // NE
    int*      rank   = pos + NE;                  // NE
    int*      count  = rank + NE;                 // NN
    int*      rowptr = count + NN;                // NN
    ushort_t* esrc   = (ushort_t*)(rowptr + NN);  // NE ushort
    __half*   feat16 = (__half*)(esrc + NE);      // NN*64 fp16
    __half*   hagg16 = feat16 + NN * 64;          // NN*64 fp16

    dim3 b64x4(64, 4);
    k_prep  <<<NN * 64 / 1024, 256, 0, stream>>>(feat, feat16, count);
    k_count <<<NE / 256, 256, 0, stream>>>(dst, count, rank);
    k_scan  <<<(NN + 255) / 256, 256, 0, stream>>>(count, rowptr);
    k_fill  <<<NE / 256, 256, 0, stream>>>(src, dst, rowptr, rank, esrc, pos);
    k_aggemm<<<NN / 8, b64x4, 0, stream>>>(feat16, W, rowptr, count, esrc,
                                           hagg, hagg16);
    k_soft  <<<NN / 4, b64x4, 0, stream>>>(hagg, hagg16, rowptr, count, esrc, ebuf);
    k_remap <<<(NE / 4 + 255) / 256, 256, 0, stream>>>(pos, ebuf, e_soft);
}